// Round 1
// baseline (2500.008 us; speedup 1.0000x reference)
//
#include <hip/hip_runtime.h>
#include <math.h>

// Problem constants
#define NROWS 16384   // 32*512
#define H     768
#define BM    128
#define BN    128
#define BK    4       // input channels per K-step
#define KK    36      // BK * 9 expanded-K per step
#define LDP   132     // LDS pitch (128 + 4) to break bank conflicts, keeps 16B alignment

// ---- KAN feature expansion: f[0]=silu(x), f[1..8]=cubic B-spline bases ----
// Faithful to the reference Cox-de Boor recursion on knots g[j] = (j-3)*0.4 - 1.
// All knots and reciprocal denominators fold to compile-time constants.
__device__ __forceinline__ void kan_features(float x, float* __restrict__ f) {
    f[0] = x / (1.0f + __expf(-x));   // silu
    float B[11];
#pragma unroll
    for (int j = 0; j < 11; ++j) {
        float gj  = (float)(j - 3) * 0.4f - 1.0f;
        float gj1 = (float)(j - 2) * 0.4f - 1.0f;
        B[j] = (x >= gj && x < gj1) ? 1.0f : 0.0f;
    }
#pragma unroll
    for (int p = 1; p <= 3; ++p) {
#pragma unroll
        for (int j = 0; j < 11 - p; ++j) {
            float gj   = (float)(j - 3) * 0.4f - 1.0f;
            float gj1  = (float)(j - 2) * 0.4f - 1.0f;
            float gjp  = (float)(j + p - 3) * 0.4f - 1.0f;
            float gjp1 = (float)(j + p - 2) * 0.4f - 1.0f;
            float rl = 1.0f / (gjp - gj);    // compile-time constant
            float rr = 1.0f / (gjp1 - gj1);  // compile-time constant
            B[j] = (x - gj) * rl * B[j] + (gjp1 - x) * rr * B[j + 1];
        }
    }
#pragma unroll
    for (int c = 0; c < 8; ++c) f[c + 1] = B[c];
}

__device__ __forceinline__ float gelu_exact(float x) {
    return 0.5f * x * (1.0f + erff(x * 0.70710678118654752f));
}

// ---- Layer 1: fused feature expansion + fp32 GEMM (N x 768, K'=6912) ----
// grid = (6 col-tiles, 128 row-tiles), 256 threads, 8x8 micro-tile per thread.
__global__ __launch_bounds__(256) void kan1_kernel(
    const float* __restrict__ x, const float* __restrict__ bw,
    const float* __restrict__ sw, const float* __restrict__ sc,
    float* __restrict__ out)
{
    __shared__ __align__(16) float sA[KK * LDP];
    __shared__ __align__(16) float sB[KK * LDP];
    const int t = threadIdx.x;
    const int rowBase = blockIdx.y * BM;
    const int colBase = blockIdx.x * BN;
    const int tx = t & 15;    // row group
    const int ty = t >> 4;    // col group
    float acc[8][8] = {};

    for (int kt = 0; kt < H / BK; ++kt) {
        const int i0 = kt * BK;
        // Stage A: features of x for 128 rows x BK channels (512 elems, 2/thread)
#pragma unroll
        for (int q = 0; q < 2; ++q) {
            int e = t + 256 * q;
            int r = e & 127, il = e >> 7;
            float xv = x[(size_t)(rowBase + r) * H + (i0 + il)];
            float f[9];
            kan_features(xv, f);
#pragma unroll
            for (int c = 0; c < 9; ++c) sA[(il * 9 + c) * LDP + r] = f[c];
        }
        // Stage B: combined weights [base_w | spline_w*scaler] for 128 cols x BK
#pragma unroll
        for (int q = 0; q < 2; ++q) {
            int e = t + 256 * q;
            int col = e & 127, il = e >> 7;
            size_t off = (size_t)(colBase + col) * H + (i0 + il);
            float b = bw[off];
            float s = sc[off];
            const float4* wp = (const float4*)(sw + off * 8);
            float4 w0 = wp[0], w1 = wp[1];
            int base = il * 9;
            sB[(base + 0) * LDP + col] = b;
            sB[(base + 1) * LDP + col] = w0.x * s;
            sB[(base + 2) * LDP + col] = w0.y * s;
            sB[(base + 3) * LDP + col] = w0.z * s;
            sB[(base + 4) * LDP + col] = w0.w * s;
            sB[(base + 5) * LDP + col] = w1.x * s;
            sB[(base + 6) * LDP + col] = w1.y * s;
            sB[(base + 7) * LDP + col] = w1.z * s;
            sB[(base + 8) * LDP + col] = w1.w * s;
        }
        __syncthreads();
#pragma unroll 12
        for (int kk = 0; kk < KK; ++kk) {
            float4 a0 = *(const float4*)&sA[kk * LDP + tx * 8];
            float4 a1 = *(const float4*)&sA[kk * LDP + tx * 8 + 4];
            float4 b0 = *(const float4*)&sB[kk * LDP + ty * 8];
            float4 b1 = *(const float4*)&sB[kk * LDP + ty * 8 + 4];
            float av[8] = {a0.x, a0.y, a0.z, a0.w, a1.x, a1.y, a1.z, a1.w};
            float bv[8] = {b0.x, b0.y, b0.z, b0.w, b1.x, b1.y, b1.z, b1.w};
#pragma unroll
            for (int rr = 0; rr < 8; ++rr)
#pragma unroll
                for (int cc = 0; cc < 8; ++cc)
                    acc[rr][cc] = fmaf(av[rr], bv[cc], acc[rr][cc]);
        }
        __syncthreads();
    }
    // Store raw (pre-GELU) layer-1 output
#pragma unroll
    for (int rr = 0; rr < 8; ++rr) {
        size_t rowoff = (size_t)(rowBase + tx * 8 + rr) * H + colBase + ty * 8;
        float4 v0 = make_float4(acc[rr][0], acc[rr][1], acc[rr][2], acc[rr][3]);
        float4 v1 = make_float4(acc[rr][4], acc[rr][5], acc[rr][6], acc[rr][7]);
        *(float4*)&out[rowoff]     = v0;
        *(float4*)&out[rowoff + 4] = v1;
    }
}

// ---- Layer 2: fused GELU + feature expansion + (768*9 -> 2) reduction ----
// One wave per row; 4 waves (rows) per block.
__global__ __launch_bounds__(256) void kan2_kernel(
    const float* __restrict__ l1, const float* __restrict__ bw,
    const float* __restrict__ sw, const float* __restrict__ sc,
    float* __restrict__ out)
{
    const int lane = threadIdx.x & 63;
    const int wv = threadIdx.x >> 6;
    const int n = blockIdx.x * 4 + wv;
    float a0 = 0.f, a1 = 0.f;
#pragma unroll
    for (int ii = 0; ii < H / 64; ++ii) {
        int i = lane + ii * 64;
        float h = l1[(size_t)n * H + i];
        float u = gelu_exact(h);
        float f[9];
        kan_features(u, f);
        float b0 = bw[i], b1 = bw[H + i];
        float s0 = sc[i], s1 = sc[H + i];
        const float4* p0 = (const float4*)(sw + (size_t)i * 8);
        const float4* p1 = (const float4*)(sw + (size_t)(H + i) * 8);
        float4 w00 = p0[0], w01 = p0[1];
        float4 w10 = p1[0], w11 = p1[1];
        float t0 = f[1] * w00.x + f[2] * w00.y + f[3] * w00.z + f[4] * w00.w
                 + f[5] * w01.x + f[6] * w01.y + f[7] * w01.z + f[8] * w01.w;
        float t1 = f[1] * w10.x + f[2] * w10.y + f[3] * w10.z + f[4] * w10.w
                 + f[5] * w11.x + f[6] * w11.y + f[7] * w11.z + f[8] * w11.w;
        a0 += f[0] * b0 + s0 * t0;
        a1 += f[0] * b1 + s1 * t1;
    }
#pragma unroll
    for (int off = 32; off > 0; off >>= 1) {
        a0 += __shfl_down(a0, off, 64);
        a1 += __shfl_down(a1, off, 64);
    }
    if (lane == 0) {
        out[(size_t)n * 2 + 0] = a0;
        out[(size_t)n * 2 + 1] = a1;
    }
}

extern "C" void kernel_launch(void* const* d_in, const int* in_sizes, int n_in,
                              void* d_out, int out_size, void* d_ws, size_t ws_size,
                              hipStream_t stream) {
    const float* hidden = (const float*)d_in[0];
    const float* bw1    = (const float*)d_in[1];
    const float* sw1    = (const float*)d_in[2];
    const float* sc1    = (const float*)d_in[3];
    const float* bw2    = (const float*)d_in[4];
    const float* sw2    = (const float*)d_in[5];
    const float* sc2    = (const float*)d_in[6];
    float* out = (float*)d_out;
    float* l1  = (float*)d_ws;   // 16384*768 fp32 = 50.3 MB scratch

    kan1_kernel<<<dim3(H / BN, NROWS / BM), 256, 0, stream>>>(hidden, bw1, sw1, sc1, l1);
    kan2_kernel<<<NROWS / 4, 256, 0, stream>>>(l1, bw2, sw2, sc2, out);
}

// Round 2
// 781.856 us; speedup vs baseline: 3.1975x; 3.1975x over previous
//
#include <hip/hip_runtime.h>
#include <math.h>

// Problem constants
#define NROWS 16384   // 32*512
#define H     768
#define KEXP  6912    // 768 (silu*base_w) + 768*8 (bases*spline_w*scaler)
#define NSILU 12      // silu k-chunks of 64
#define NSPL  96      // spline k-chunks of 64
#define NCHUNK 108

typedef __attribute__((ext_vector_type(8))) short  bhalf8;
typedef __attribute__((ext_vector_type(4))) float  floatx4;

__device__ __forceinline__ unsigned short f2bf(float f) {
    unsigned int u = __float_as_uint(f);
    u = (u + 0x7FFFu + ((u >> 16) & 1u)) >> 16;   // RNE
    return (unsigned short)u;
}
__device__ __forceinline__ float bf2f(unsigned short h) {
    return __uint_as_float(((unsigned int)h) << 16);
}
__device__ __forceinline__ unsigned int pack2(unsigned short a, unsigned short b) {
    return (unsigned int)a | ((unsigned int)b << 16);
}
__device__ __forceinline__ float silu_f(float x) { return x / (1.0f + __expf(-x)); }
__device__ __forceinline__ float gelu_exact(float x) {
    return 0.5f * x * (1.0f + erff(x * 0.70710678118654752f));
}

// 8 cubic B-spline bases, faithful Cox-de Boor on knots g[j] = (j-3)*0.4 - 1
__device__ __forceinline__ void kan_bases(float x, float* __restrict__ b) {
    float B[11];
#pragma unroll
    for (int j = 0; j < 11; ++j) {
        float gj  = (float)(j - 3) * 0.4f - 1.0f;
        float gj1 = (float)(j - 2) * 0.4f - 1.0f;
        B[j] = (x >= gj && x < gj1) ? 1.0f : 0.0f;
    }
#pragma unroll
    for (int p = 1; p <= 3; ++p) {
#pragma unroll
        for (int j = 0; j < 11 - p; ++j) {
            float gj   = (float)(j - 3) * 0.4f - 1.0f;
            float gj1  = (float)(j - 2) * 0.4f - 1.0f;
            float gjp  = (float)(j + p - 3) * 0.4f - 1.0f;
            float gjp1 = (float)(j + p - 2) * 0.4f - 1.0f;
            float rl = 1.0f / (gjp - gj);
            float rr = 1.0f / (gjp1 - gj1);
            B[j] = (x - gj) * rl * B[j] + (gjp1 - x) * rr * B[j + 1];
        }
    }
#pragma unroll
    for (int c = 0; c < 8; ++c) b[c] = B[c];
}

// ---- Build W' bf16 [768][6912]: row n = [ bw1[n][:] | sw1[n][i][c]*sc1[n][i] ]
__global__ __launch_bounds__(256) void prep_w1(
    const float* __restrict__ bw, const float* __restrict__ sw,
    const float* __restrict__ sc, unsigned short* __restrict__ wp)
{
    const int n = blockIdx.x, t = threadIdx.x;
    const float* bwr = bw + (size_t)n * H;
    unsigned short* out = wp + (size_t)n * KEXP;
    for (int k = t; k < H; k += 256) out[k] = f2bf(bwr[k]);
#pragma unroll
    for (int p = 0; p < 3; ++p) {
        int i = t + p * 256;
        float s = sc[(size_t)n * H + i];
        const float4* swp = (const float4*)(sw + ((size_t)n * H + i) * 8);
        float4 w0 = swp[0], w1 = swp[1];
        uint4 pk;
        pk.x = pack2(f2bf(w0.x * s), f2bf(w0.y * s));
        pk.y = pack2(f2bf(w0.z * s), f2bf(w0.w * s));
        pk.z = pack2(f2bf(w1.x * s), f2bf(w1.y * s));
        pk.w = pack2(f2bf(w1.z * s), f2bf(w1.w * s));
        *(uint4*)(out + H + (size_t)i * 8) = pk;
    }
}

// ---- Layer 1: bf16 MFMA GEMM, A = inline KAN features, B = W' via global_load_lds.
// 128x128 tile, BK=64 (8 granules of 8 bf16), XOR-granule swizzle on both LDS tiles.
__global__ __launch_bounds__(256, 3) void kan1_mfma(
    const float* __restrict__ x, const unsigned short* __restrict__ wp,
    unsigned short* __restrict__ l1)
{
    __shared__ __align__(16) unsigned short sA[128 * 64];
    __shared__ __align__(16) unsigned short sB[128 * 64];
    const int t = threadIdx.x;
    const int lane = t & 63, wv = t >> 6;
    const int quad = lane >> 4, lm = lane & 15;
    const int wr = wv & 1, wc = wv >> 1;
    const int rowBase = blockIdx.y * 128, colBase = blockIdx.x * 128;
    const int p7 = lm & 7;

    floatx4 acc[4][4] = {};
    int aoff[4], boff[4], goff[2];
#pragma unroll
    for (int im = 0; im < 4; ++im) aoff[im] = (wr * 64 + im * 16 + lm) * 64;
#pragma unroll
    for (int in_ = 0; in_ < 4; ++in_) boff[in_] = (wc * 64 + in_ * 16 + lm) * 64;
#pragma unroll
    for (int kk = 0; kk < 2; ++kk) goff[kk] = ((kk * 4 + quad) ^ p7) * 8;

    // B staging lane constants
    const int br_off = lane >> 3;           // row within 8-row segment
    const int bg_slot = lane & 7;           // lds granule slot

#pragma unroll 1
    for (int kc = 0; kc < NCHUNK; ++kc) {
        // ---- stage A (VALU features -> LDS, swizzled) ----
        if (kc < NSILU) {
            const int i0 = kc * 64;
#pragma unroll
            for (int q = 0; q < 4; ++q) {
                int e = t + 256 * q;
                int r = e >> 3, gc = e & 7;
                const float* xp = x + (size_t)(rowBase + r) * H + i0 + gc * 8;
                float4 v0 = *(const float4*)xp, v1 = *(const float4*)(xp + 4);
                uint4 pk;
                pk.x = pack2(f2bf(silu_f(v0.x)), f2bf(silu_f(v0.y)));
                pk.y = pack2(f2bf(silu_f(v0.z)), f2bf(silu_f(v0.w)));
                pk.z = pack2(f2bf(silu_f(v1.x)), f2bf(silu_f(v1.y)));
                pk.w = pack2(f2bf(silu_f(v1.z)), f2bf(silu_f(v1.w)));
                *(uint4*)&sA[(r * 8 + (gc ^ (r & 7))) * 8] = pk;
            }
        } else {
            const int i0 = (kc - NSILU) * 8;
#pragma unroll
            for (int q = 0; q < 4; ++q) {
                int e = t + 256 * q;
                int r = e >> 3, c8 = e & 7;
                float xv = x[(size_t)(rowBase + r) * H + i0 + c8];
                float b[8];
                kan_bases(xv, b);
                uint4 pk;
                pk.x = pack2(f2bf(b[0]), f2bf(b[1]));
                pk.y = pack2(f2bf(b[2]), f2bf(b[3]));
                pk.z = pack2(f2bf(b[4]), f2bf(b[5]));
                pk.w = pack2(f2bf(b[6]), f2bf(b[7]));
                *(uint4*)&sA[(r * 8 + (c8 ^ (r & 7))) * 8] = pk;
            }
        }
        // ---- stage B: W' -> LDS via global_load_lds (source-swizzled) ----
#pragma unroll
        for (int p = 0; p < 4; ++p) {
            int s = wv * 4 + p;
            int r = s * 8 + br_off;
            int g = bg_slot ^ (r & 7);
            const unsigned short* gp = wp + (size_t)(colBase + r) * KEXP + kc * 64 + g * 8;
            unsigned short* lp = sB + s * 512;
            __builtin_amdgcn_global_load_lds(
                (const __attribute__((address_space(1))) void*)gp,
                (__attribute__((address_space(3))) void*)lp, 16, 0, 0);
        }
        __syncthreads();
        // ---- MFMA: 2 k-steps x 4x4 tiles ----
#pragma unroll
        for (int kk = 0; kk < 2; ++kk) {
            bhalf8 af[4], bf[4];
#pragma unroll
            for (int im = 0; im < 4; ++im) af[im] = *(const bhalf8*)&sA[aoff[im] + goff[kk]];
#pragma unroll
            for (int in_ = 0; in_ < 4; ++in_) bf[in_] = *(const bhalf8*)&sB[boff[in_] + goff[kk]];
#pragma unroll
            for (int im = 0; im < 4; ++im)
#pragma unroll
                for (int in_ = 0; in_ < 4; ++in_)
                    acc[im][in_] = __builtin_amdgcn_mfma_f32_16x16x32_bf16(
                        af[im], bf[in_], acc[im][in_], 0, 0, 0);
        }
        __syncthreads();
    }
    // ---- epilogue: store pre-GELU l1 as bf16 ----
#pragma unroll
    for (int im = 0; im < 4; ++im) {
#pragma unroll
        for (int in_ = 0; in_ < 4; ++in_) {
            int col = colBase + wc * 64 + in_ * 16 + lm;
            size_t rbase = (size_t)(rowBase + wr * 64 + im * 16 + quad * 4);
#pragma unroll
            for (int reg = 0; reg < 4; ++reg)
                l1[(rbase + reg) * H + col] = f2bf(acc[im][in_][reg]);
        }
    }
}

// ---- Layer 2: GELU + features + (768*9 -> 2), one wave per row ----
__global__ __launch_bounds__(256) void kan2_kernel(
    const unsigned short* __restrict__ l1, const float* __restrict__ bw,
    const float* __restrict__ sw, const float* __restrict__ sc,
    float* __restrict__ out)
{
    const int lane = threadIdx.x & 63;
    const int wv = threadIdx.x >> 6;
    const int n = blockIdx.x * 4 + wv;
    float a0 = 0.f, a1 = 0.f;
#pragma unroll
    for (int ii = 0; ii < H / 64; ++ii) {
        int i = lane + ii * 64;
        float h = bf2f(l1[(size_t)n * H + i]);
        float u = gelu_exact(h);
        float f0 = silu_f(u);
        float b[8];
        kan_bases(u, b);
        float bw0 = bw[i], bw1 = bw[H + i];
        float s0 = sc[i], s1 = sc[H + i];
        const float4* p0 = (const float4*)(sw + (size_t)i * 8);
        const float4* p1 = (const float4*)(sw + (size_t)(H + i) * 8);
        float4 w00 = p0[0], w01 = p0[1];
        float4 w10 = p1[0], w11 = p1[1];
        float t0 = b[0] * w00.x + b[1] * w00.y + b[2] * w00.z + b[3] * w00.w
                 + b[4] * w01.x + b[5] * w01.y + b[6] * w01.z + b[7] * w01.w;
        float t1 = b[0] * w10.x + b[1] * w10.y + b[2] * w10.z + b[3] * w10.w
                 + b[4] * w11.x + b[5] * w11.y + b[6] * w11.z + b[7] * w11.w;
        a0 += f0 * bw0 + s0 * t0;
        a1 += f0 * bw1 + s1 * t1;
    }
#pragma unroll
    for (int off = 32; off > 0; off >>= 1) {
        a0 += __shfl_down(a0, off, 64);
        a1 += __shfl_down(a1, off, 64);
    }
    if (lane == 0) {
        out[(size_t)n * 2 + 0] = a0;
        out[(size_t)n * 2 + 1] = a1;
    }
}

extern "C" void kernel_launch(void* const* d_in, const int* in_sizes, int n_in,
                              void* d_out, int out_size, void* d_ws, size_t ws_size,
                              hipStream_t stream) {
    const float* hidden = (const float*)d_in[0];
    const float* bw1    = (const float*)d_in[1];
    const float* sw1    = (const float*)d_in[2];
    const float* sc1    = (const float*)d_in[3];
    const float* bw2    = (const float*)d_in[4];
    const float* sw2    = (const float*)d_in[5];
    const float* sc2    = (const float*)d_in[6];
    float* out = (float*)d_out;

    unsigned short* l1 = (unsigned short*)d_ws;                       // 25.2 MB bf16
    unsigned short* wp = (unsigned short*)d_ws + (size_t)NROWS * H;   // 10.6 MB bf16

    prep_w1<<<H, 256, 0, stream>>>(bw1, sw1, sc1, wp);
    kan1_mfma<<<dim3(H / 128, NROWS / 128), 256, 0, stream>>>(hidden, wp, l1);
    kan2_kernel<<<NROWS / 4, 256, 0, stream>>>(l1, bw2, sw2, sc2, out);
}

// Round 3
// 540.344 us; speedup vs baseline: 4.6267x; 1.4470x over previous
//
#include <hip/hip_runtime.h>
#include <math.h>

// Problem constants
#define NROWS 16384   // 32*512
#define H     768
#define KEXP  6912    // 768 (silu*base_w) + 768*8 (bases*spline_w*scaler)
#define NSILU 12      // silu k-chunks of 64
#define NCHUNK 108    // KEXP/64

typedef __attribute__((ext_vector_type(8))) short  bhalf8;
typedef __attribute__((ext_vector_type(4))) float  floatx4;

__device__ __forceinline__ unsigned short f2bf(float f) {
    unsigned int u = __float_as_uint(f);
    u = (u + 0x7FFFu + ((u >> 16) & 1u)) >> 16;   // RNE
    return (unsigned short)u;
}
__device__ __forceinline__ float bf2f(unsigned short h) {
    return __uint_as_float(((unsigned int)h) << 16);
}
__device__ __forceinline__ unsigned int pack2(unsigned short a, unsigned short b) {
    return (unsigned int)a | ((unsigned int)b << 16);
}
__device__ __forceinline__ float silu_f(float x) { return x / (1.0f + __expf(-x)); }
__device__ __forceinline__ float gelu_exact(float x) {
    return 0.5f * x * (1.0f + erff(x * 0.70710678118654752f));
}

// 8 cubic B-spline bases, faithful Cox-de Boor on knots g[j] = (j-3)*0.4 - 1
__device__ __forceinline__ void kan_bases(float x, float* __restrict__ b) {
    float B[11];
#pragma unroll
    for (int j = 0; j < 11; ++j) {
        float gj  = (float)(j - 3) * 0.4f - 1.0f;
        float gj1 = (float)(j - 2) * 0.4f - 1.0f;
        B[j] = (x >= gj && x < gj1) ? 1.0f : 0.0f;
    }
#pragma unroll
    for (int p = 1; p <= 3; ++p) {
#pragma unroll
        for (int j = 0; j < 11 - p; ++j) {
            float gj   = (float)(j - 3) * 0.4f - 1.0f;
            float gj1  = (float)(j - 2) * 0.4f - 1.0f;
            float gjp  = (float)(j + p - 3) * 0.4f - 1.0f;
            float gjp1 = (float)(j + p - 2) * 0.4f - 1.0f;
            float rl = 1.0f / (gjp - gj);
            float rr = 1.0f / (gjp1 - gj1);
            B[j] = (x - gj) * rl * B[j] + (gjp1 - x) * rr * B[j + 1];
        }
    }
#pragma unroll
    for (int c = 0; c < 8; ++c) b[c] = B[c];
}

// ---- Build W' bf16 [768][6912]: row n = [ bw1[n][:] | sw1[n][i][c]*sc1[n][i] ]
__global__ __launch_bounds__(256) void prep_w1(
    const float* __restrict__ bw, const float* __restrict__ sw,
    const float* __restrict__ sc, unsigned short* __restrict__ wp)
{
    const int n = blockIdx.x, t = threadIdx.x;
    const float* bwr = bw + (size_t)n * H;
    unsigned short* out = wp + (size_t)n * KEXP;
    for (int k = t; k < H; k += 256) out[k] = f2bf(bwr[k]);
#pragma unroll
    for (int p = 0; p < 3; ++p) {
        int i = t + p * 256;
        float s = sc[(size_t)n * H + i];
        const float4* swp = (const float4*)(sw + ((size_t)n * H + i) * 8);
        float4 w0 = swp[0], w1 = swp[1];
        uint4 pk;
        pk.x = pack2(f2bf(w0.x * s), f2bf(w0.y * s));
        pk.y = pack2(f2bf(w0.z * s), f2bf(w0.w * s));
        pk.z = pack2(f2bf(w1.x * s), f2bf(w1.y * s));
        pk.w = pack2(f2bf(w1.z * s), f2bf(w1.w * s));
        *(uint4*)(out + H + (size_t)i * 8) = pk;
    }
}

// ---- Expand: F bf16 [16384][6912], row n = [ silu(x[n][:]) | bases(x[n][i])[8] ]
__global__ __launch_bounds__(256) void expand_f(
    const float* __restrict__ x, unsigned short* __restrict__ F)
{
    const int n = blockIdx.x, t = threadIdx.x;
    unsigned short* out = F + (size_t)n * KEXP;
#pragma unroll
    for (int p = 0; p < 3; ++p) {
        int i = t + p * 256;
        float xv = x[(size_t)n * H + i];
        out[i] = f2bf(silu_f(xv));
        float b[8];
        kan_bases(xv, b);
        uint4 pk;
        pk.x = pack2(f2bf(b[0]), f2bf(b[1]));
        pk.y = pack2(f2bf(b[2]), f2bf(b[3]));
        pk.z = pack2(f2bf(b[4]), f2bf(b[5]));
        pk.w = pack2(f2bf(b[6]), f2bf(b[7]));
        *(uint4*)(out + H + (size_t)i * 8) = pk;
    }
}

// ---- Layer 1 (split path): pure bf16 MFMA GEMM, A=F, B=W', both via global_load_lds.
// 128x128 tile, BK=64, XOR-granule swizzle (round-2-verified, 0 bank conflicts).
__global__ __launch_bounds__(256) void kan1_gemm(
    const unsigned short* __restrict__ F, const unsigned short* __restrict__ wp,
    unsigned short* __restrict__ l1)
{
    __shared__ __align__(16) unsigned short sA[128 * 64];
    __shared__ __align__(16) unsigned short sB[128 * 64];
    const int t = threadIdx.x;
    const int lane = t & 63, wv = t >> 6;
    const int quad = lane >> 4, lm = lane & 15;
    const int wr = wv & 1, wc = wv >> 1;
    const int rowBase = blockIdx.y * 128, colBase = blockIdx.x * 128;
    const int p7 = lm & 7;

    floatx4 acc[4][4] = {};
    int aoff[4], boff[4], goff[2];
#pragma unroll
    for (int im = 0; im < 4; ++im) aoff[im] = (wr * 64 + im * 16 + lm) * 64;
#pragma unroll
    for (int in_ = 0; in_ < 4; ++in_) boff[in_] = (wc * 64 + in_ * 16 + lm) * 64;
#pragma unroll
    for (int kk = 0; kk < 2; ++kk) goff[kk] = ((kk * 4 + quad) ^ p7) * 8;

    const int br_off = lane >> 3;   // row within 8-row segment
    const int bg_slot = lane & 7;   // lds granule slot

#pragma unroll 1
    for (int kc = 0; kc < NCHUNK; ++kc) {
#pragma unroll
        for (int p = 0; p < 4; ++p) {
            int s = wv * 4 + p;
            int r = s * 8 + br_off;
            int g = bg_slot ^ (r & 7);
            const unsigned short* ga = F  + (size_t)(rowBase + r) * KEXP + kc * 64 + g * 8;
            const unsigned short* gb = wp + (size_t)(colBase + r) * KEXP + kc * 64 + g * 8;
            __builtin_amdgcn_global_load_lds(
                (const __attribute__((address_space(1))) void*)ga,
                (__attribute__((address_space(3))) void*)(sA + s * 512), 16, 0, 0);
            __builtin_amdgcn_global_load_lds(
                (const __attribute__((address_space(1))) void*)gb,
                (__attribute__((address_space(3))) void*)(sB + s * 512), 16, 0, 0);
        }
        __syncthreads();
#pragma unroll
        for (int kk = 0; kk < 2; ++kk) {
            bhalf8 af[4], bf[4];
#pragma unroll
            for (int im = 0; im < 4; ++im) af[im] = *(const bhalf8*)&sA[aoff[im] + goff[kk]];
#pragma unroll
            for (int in_ = 0; in_ < 4; ++in_) bf[in_] = *(const bhalf8*)&sB[boff[in_] + goff[kk]];
#pragma unroll
            for (int im = 0; im < 4; ++im)
#pragma unroll
                for (int in_ = 0; in_ < 4; ++in_)
                    acc[im][in_] = __builtin_amdgcn_mfma_f32_16x16x32_bf16(
                        af[im], bf[in_], acc[im][in_], 0, 0, 0);
        }
        __syncthreads();
    }
#pragma unroll
    for (int im = 0; im < 4; ++im) {
#pragma unroll
        for (int in_ = 0; in_ < 4; ++in_) {
            int col = colBase + wc * 64 + in_ * 16 + lm;
            size_t rbase = (size_t)(rowBase + wr * 64 + im * 16 + quad * 4);
#pragma unroll
            for (int reg = 0; reg < 4; ++reg)
                l1[(rbase + reg) * H + col] = f2bf(acc[im][in_][reg]);
        }
    }
}

// ---- Layer 1 (fallback path, ws too small): round-2 fused kernel, unchanged ----
__global__ __launch_bounds__(256, 3) void kan1_mfma(
    const float* __restrict__ x, const unsigned short* __restrict__ wp,
    unsigned short* __restrict__ l1)
{
    __shared__ __align__(16) unsigned short sA[128 * 64];
    __shared__ __align__(16) unsigned short sB[128 * 64];
    const int t = threadIdx.x;
    const int lane = t & 63, wv = t >> 6;
    const int quad = lane >> 4, lm = lane & 15;
    const int wr = wv & 1, wc = wv >> 1;
    const int rowBase = blockIdx.y * 128, colBase = blockIdx.x * 128;
    const int p7 = lm & 7;

    floatx4 acc[4][4] = {};
    int aoff[4], boff[4], goff[2];
#pragma unroll
    for (int im = 0; im < 4; ++im) aoff[im] = (wr * 64 + im * 16 + lm) * 64;
#pragma unroll
    for (int in_ = 0; in_ < 4; ++in_) boff[in_] = (wc * 64 + in_ * 16 + lm) * 64;
#pragma unroll
    for (int kk = 0; kk < 2; ++kk) goff[kk] = ((kk * 4 + quad) ^ p7) * 8;

    const int br_off = lane >> 3;
    const int bg_slot = lane & 7;

#pragma unroll 1
    for (int kc = 0; kc < NCHUNK; ++kc) {
        if (kc < NSILU) {
            const int i0 = kc * 64;
#pragma unroll
            for (int q = 0; q < 4; ++q) {
                int e = t + 256 * q;
                int r = e >> 3, gc = e & 7;
                const float* xp = x + (size_t)(rowBase + r) * H + i0 + gc * 8;
                float4 v0 = *(const float4*)xp, v1 = *(const float4*)(xp + 4);
                uint4 pk;
                pk.x = pack2(f2bf(silu_f(v0.x)), f2bf(silu_f(v0.y)));
                pk.y = pack2(f2bf(silu_f(v0.z)), f2bf(silu_f(v0.w)));
                pk.z = pack2(f2bf(silu_f(v1.x)), f2bf(silu_f(v1.y)));
                pk.w = pack2(f2bf(silu_f(v1.z)), f2bf(silu_f(v1.w)));
                *(uint4*)&sA[(r * 8 + (gc ^ (r & 7))) * 8] = pk;
            }
        } else {
            const int i0 = (kc - NSILU) * 8;
#pragma unroll
            for (int q = 0; q < 4; ++q) {
                int e = t + 256 * q;
                int r = e >> 3, c8 = e & 7;
                float xv = x[(size_t)(rowBase + r) * H + i0 + c8];
                float b[8];
                kan_bases(xv, b);
                uint4 pk;
                pk.x = pack2(f2bf(b[0]), f2bf(b[1]));
                pk.y = pack2(f2bf(b[2]), f2bf(b[3]));
                pk.z = pack2(f2bf(b[4]), f2bf(b[5]));
                pk.w = pack2(f2bf(b[6]), f2bf(b[7]));
                *(uint4*)&sA[(r * 8 + (c8 ^ (r & 7))) * 8] = pk;
            }
        }
#pragma unroll
        for (int p = 0; p < 4; ++p) {
            int s = wv * 4 + p;
            int r = s * 8 + br_off;
            int g = bg_slot ^ (r & 7);
            const unsigned short* gp = wp + (size_t)(colBase + r) * KEXP + kc * 64 + g * 8;
            __builtin_amdgcn_global_load_lds(
                (const __attribute__((address_space(1))) void*)gp,
                (__attribute__((address_space(3))) void*)(sB + s * 512), 16, 0, 0);
        }
        __syncthreads();
#pragma unroll
        for (int kk = 0; kk < 2; ++kk) {
            bhalf8 af[4], bf[4];
#pragma unroll
            for (int im = 0; im < 4; ++im) af[im] = *(const bhalf8*)&sA[aoff[im] + goff[kk]];
#pragma unroll
            for (int in_ = 0; in_ < 4; ++in_) bf[in_] = *(const bhalf8*)&sB[boff[in_] + goff[kk]];
#pragma unroll
            for (int im = 0; im < 4; ++im)
#pragma unroll
                for (int in_ = 0; in_ < 4; ++in_)
                    acc[im][in_] = __builtin_amdgcn_mfma_f32_16x16x32_bf16(
                        af[im], bf[in_], acc[im][in_], 0, 0, 0);
        }
        __syncthreads();
    }
#pragma unroll
    for (int im = 0; im < 4; ++im) {
#pragma unroll
        for (int in_ = 0; in_ < 4; ++in_) {
            int col = colBase + wc * 64 + in_ * 16 + lm;
            size_t rbase = (size_t)(rowBase + wr * 64 + im * 16 + quad * 4);
#pragma unroll
            for (int reg = 0; reg < 4; ++reg)
                l1[(rbase + reg) * H + col] = f2bf(acc[im][in_][reg]);
        }
    }
}

// ---- Layer 2: GELU + features + (768*9 -> 2), one wave per row ----
__global__ __launch_bounds__(256) void kan2_kernel(
    const unsigned short* __restrict__ l1, const float* __restrict__ bw,
    const float* __restrict__ sw, const float* __restrict__ sc,
    float* __restrict__ out)
{
    const int lane = threadIdx.x & 63;
    const int wv = threadIdx.x >> 6;
    const int n = blockIdx.x * 4 + wv;
    float a0 = 0.f, a1 = 0.f;
#pragma unroll
    for (int ii = 0; ii < H / 64; ++ii) {
        int i = lane + ii * 64;
        float h = bf2f(l1[(size_t)n * H + i]);
        float u = gelu_exact(h);
        float f0 = silu_f(u);
        float b[8];
        kan_bases(u, b);
        float bw0 = bw[i], bw1 = bw[H + i];
        float s0 = sc[i], s1 = sc[H + i];
        const float4* p0 = (const float4*)(sw + (size_t)i * 8);
        const float4* p1 = (const float4*)(sw + (size_t)(H + i) * 8);
        float4 w00 = p0[0], w01 = p0[1];
        float4 w10 = p1[0], w11 = p1[1];
        float t0 = b[0] * w00.x + b[1] * w00.y + b[2] * w00.z + b[3] * w00.w
                 + b[4] * w01.x + b[5] * w01.y + b[6] * w01.z + b[7] * w01.w;
        float t1 = b[0] * w10.x + b[1] * w10.y + b[2] * w10.z + b[3] * w10.w
                 + b[4] * w11.x + b[5] * w11.y + b[6] * w11.z + b[7] * w11.w;
        a0 += f0 * bw0 + s0 * t0;
        a1 += f0 * bw1 + s1 * t1;
    }
#pragma unroll
    for (int off = 32; off > 0; off >>= 1) {
        a0 += __shfl_down(a0, off, 64);
        a1 += __shfl_down(a1, off, 64);
    }
    if (lane == 0) {
        out[(size_t)n * 2 + 0] = a0;
        out[(size_t)n * 2 + 1] = a1;
    }
}

extern "C" void kernel_launch(void* const* d_in, const int* in_sizes, int n_in,
                              void* d_out, int out_size, void* d_ws, size_t ws_size,
                              hipStream_t stream) {
    const float* hidden = (const float*)d_in[0];
    const float* bw1    = (const float*)d_in[1];
    const float* sw1    = (const float*)d_in[2];
    const float* sc1    = (const float*)d_in[3];
    const float* bw2    = (const float*)d_in[4];
    const float* sw2    = (const float*)d_in[5];
    const float* sc2    = (const float*)d_in[6];
    float* out = (float*)d_out;

    const size_t l1_elems = (size_t)NROWS * H;     // 12.58M shorts = 25.2 MB
    const size_t wp_elems = (size_t)H * KEXP;      //  5.31M shorts = 10.6 MB
    const size_t f_elems  = (size_t)NROWS * KEXP;  // 113.2M shorts = 226.5 MB

    unsigned short* l1 = (unsigned short*)d_ws;
    unsigned short* wp = l1 + l1_elems;

    prep_w1<<<H, 256, 0, stream>>>(bw1, sw1, sc1, wp);
    if (ws_size >= (l1_elems + wp_elems + f_elems) * sizeof(unsigned short)) {
        // Split path: materialize features once, then pure MFMA GEMM.
        unsigned short* F = wp + wp_elems;
        expand_f<<<NROWS, 256, 0, stream>>>(hidden, F);
        kan1_gemm<<<dim3(H / 128, NROWS / 128), 256, 0, stream>>>(F, wp, l1);
    } else {
        // Fallback (round-2 fused kernel) if workspace is too small.
        kan1_mfma<<<dim3(H / 128, NROWS / 128), 256, 0, stream>>>(hidden, wp, l1);
    }
    kan2_kernel<<<NROWS / 4, 256, 0, stream>>>(l1, bw2, sw2, sc2, out);
}

// Round 4
// 482.684 us; speedup vs baseline: 5.1794x; 1.1195x over previous
//
#include <hip/hip_runtime.h>
#include <math.h>

// Problem constants
#define NROWS 16384   // 32*512
#define H     768
#define KEXP  6912    // 768 (silu*base_w) + 768*8 (bases*spline_w*scaler)
#define NCHUNK 108    // KEXP/64

typedef __attribute__((ext_vector_type(8))) short  bhalf8;
typedef __attribute__((ext_vector_type(4))) float  floatx4;

__device__ __forceinline__ unsigned short f2bf(float f) {
    unsigned int u = __float_as_uint(f);
    u = (u + 0x7FFFu + ((u >> 16) & 1u)) >> 16;   // RNE
    return (unsigned short)u;
}
__device__ __forceinline__ float bf2f(unsigned short h) {
    return __uint_as_float(((unsigned int)h) << 16);
}
__device__ __forceinline__ unsigned int pack2(unsigned short a, unsigned short b) {
    return (unsigned int)a | ((unsigned int)b << 16);
}
__device__ __forceinline__ float silu_f(float x) { return x / (1.0f + __expf(-x)); }
__device__ __forceinline__ float gelu_exact(float x) {
    return 0.5f * x * (1.0f + erff(x * 0.70710678118654752f));
}

// Closed-form cubic B-spline bases on uniform knots g[j] = (j-3)*0.4 - 1.
// For x in interval j0 (g[j0] <= x < g[j0+1]), only bases c = j0-3..j0 are
// nonzero, with the standard uniform cubic values in t = (x - g[j0])/h.
// Algebraically identical to the reference Cox-de Boor recursion (edge bases
// c=0..7 all have full knot support; x outside [-2.2, 2.2) -> all zero,
// which the d-in-[0,3] test gives automatically).
__device__ __forceinline__ void kan_bases(float x, float* __restrict__ b) {
    const float c6 = 0.166666666667f;
    float u  = fmaf(x, 2.5f, 5.5f);      // (x + 2.2) / 0.4
    float fj = floorf(u);
    float t  = u - fj;                    // in [0,1)
    int  j0  = (int)fj;
    float t2 = t * t, t3 = t2 * t;
    float n0 = t3 * c6;                                             // d=0: t^3/6
    float n1 = fmaf(t3, -0.5f, fmaf(t2, 0.5f, fmaf(t, 0.5f, c6)));  // d=1
    float n2 = fmaf(t3, 0.5f, fmaf(t2, -1.0f, 0.666666666667f));    // d=2
    float omt = 1.0f - t;
    float n3 = omt * omt * omt * c6;                                // d=3: (1-t)^3/6
#pragma unroll
    for (int c = 0; c < 8; ++c) {
        int d = j0 - c;
        float v = (d == 0) ? n0 : 0.0f;
        v = (d == 1) ? n1 : v;
        v = (d == 2) ? n2 : v;
        v = (d == 3) ? n3 : v;
        b[c] = v;
    }
}

// ---- Build W' bf16 [768][6912]: row n = [ bw1[n][:] | sw1[n][i][c]*sc1[n][i] ]
__global__ __launch_bounds__(256) void prep_w1(
    const float* __restrict__ bw, const float* __restrict__ sw,
    const float* __restrict__ sc, unsigned short* __restrict__ wp)
{
    const int n = blockIdx.x, t = threadIdx.x;
    const float* bwr = bw + (size_t)n * H;
    unsigned short* out = wp + (size_t)n * KEXP;
    for (int k = t; k < H; k += 256) out[k] = f2bf(bwr[k]);
#pragma unroll
    for (int p = 0; p < 3; ++p) {
        int i = t + p * 256;
        float s = sc[(size_t)n * H + i];
        const float4* swp = (const float4*)(sw + ((size_t)n * H + i) * 8);
        float4 w0 = swp[0], w1 = swp[1];
        uint4 pk;
        pk.x = pack2(f2bf(w0.x * s), f2bf(w0.y * s));
        pk.y = pack2(f2bf(w0.z * s), f2bf(w0.w * s));
        pk.z = pack2(f2bf(w1.x * s), f2bf(w1.y * s));
        pk.w = pack2(f2bf(w1.z * s), f2bf(w1.w * s));
        *(uint4*)(out + H + (size_t)i * 8) = pk;
    }
}

// ---- Expand: F bf16 [16384][6912], row n = [ silu(x[n][:]) | bases(x[n][i])[8] ]
__global__ __launch_bounds__(256) void expand_f(
    const float* __restrict__ x, unsigned short* __restrict__ F)
{
    const int n = blockIdx.x, t = threadIdx.x;
    unsigned short* out = F + (size_t)n * KEXP;
#pragma unroll
    for (int p = 0; p < 3; ++p) {
        int i = t + p * 256;
        float xv = x[(size_t)n * H + i];
        out[i] = f2bf(silu_f(xv));
        float b[8];
        kan_bases(xv, b);
        uint4 pk;
        pk.x = pack2(f2bf(b[0]), f2bf(b[1]));
        pk.y = pack2(f2bf(b[2]), f2bf(b[3]));
        pk.z = pack2(f2bf(b[4]), f2bf(b[5]));
        pk.w = pack2(f2bf(b[6]), f2bf(b[7]));
        *(uint4*)(out + H + (size_t)i * 8) = pk;
    }
}

// ---- Layer 1: pure bf16 MFMA GEMM, A=F, B=W', both via global_load_lds.
// 128x128 tile, BK=64, XOR-granule swizzle (0 bank conflicts, verified r2/r3).
// XCD-aware block swizzle: the 6 col-tiles of one F row-panel are adjacent in
// dispatch order on the SAME XCD -> panel re-reads hit that XCD's 4MB L2.
__global__ __launch_bounds__(256) void kan1_gemm(
    const unsigned short* __restrict__ F, const unsigned short* __restrict__ wp,
    unsigned short* __restrict__ l1)
{
    __shared__ __align__(16) unsigned short sA[128 * 64];
    __shared__ __align__(16) unsigned short sB[128 * 64];
    const int b = blockIdx.x;          // 0..767
    const int xcd = b & 7, s = b >> 3; // s in 0..95
    const int rowT = xcd * 16 + s / 6; // 0..127
    const int colT = s % 6;            // 0..5
    const int rowBase = rowT * 128, colBase = colT * 128;

    const int t = threadIdx.x;
    const int lane = t & 63, wv = t >> 6;
    const int quad = lane >> 4, lm = lane & 15;
    const int wr = wv & 1, wc = wv >> 1;
    const int p7 = lm & 7;

    floatx4 acc[4][4] = {};
    int aoff[4], boff[4], goff[2];
#pragma unroll
    for (int im = 0; im < 4; ++im) aoff[im] = (wr * 64 + im * 16 + lm) * 64;
#pragma unroll
    for (int in_ = 0; in_ < 4; ++in_) boff[in_] = (wc * 64 + in_ * 16 + lm) * 64;
#pragma unroll
    for (int kk = 0; kk < 2; ++kk) goff[kk] = ((kk * 4 + quad) ^ p7) * 8;

    const int br_off = lane >> 3;   // row within 8-row segment
    const int bg_slot = lane & 7;   // lds granule slot

#pragma unroll 1
    for (int kc = 0; kc < NCHUNK; ++kc) {
#pragma unroll
        for (int p = 0; p < 4; ++p) {
            int sseg = wv * 4 + p;
            int r = sseg * 8 + br_off;
            int g = bg_slot ^ (r & 7);
            const unsigned short* ga = F  + (size_t)(rowBase + r) * KEXP + kc * 64 + g * 8;
            const unsigned short* gb = wp + (size_t)(colBase + r) * KEXP + kc * 64 + g * 8;
            __builtin_amdgcn_global_load_lds(
                (const __attribute__((address_space(1))) void*)ga,
                (__attribute__((address_space(3))) void*)(sA + sseg * 512), 16, 0, 0);
            __builtin_amdgcn_global_load_lds(
                (const __attribute__((address_space(1))) void*)gb,
                (__attribute__((address_space(3))) void*)(sB + sseg * 512), 16, 0, 0);
        }
        __syncthreads();
#pragma unroll
        for (int kk = 0; kk < 2; ++kk) {
            bhalf8 af[4], bf[4];
#pragma unroll
            for (int im = 0; im < 4; ++im) af[im] = *(const bhalf8*)&sA[aoff[im] + goff[kk]];
#pragma unroll
            for (int in_ = 0; in_ < 4; ++in_) bf[in_] = *(const bhalf8*)&sB[boff[in_] + goff[kk]];
#pragma unroll
            for (int im = 0; im < 4; ++im)
#pragma unroll
                for (int in_ = 0; in_ < 4; ++in_)
                    acc[im][in_] = __builtin_amdgcn_mfma_f32_16x16x32_bf16(
                        af[im], bf[in_], acc[im][in_], 0, 0, 0);
        }
        __syncthreads();
    }
#pragma unroll
    for (int im = 0; im < 4; ++im) {
#pragma unroll
        for (int in_ = 0; in_ < 4; ++in_) {
            int col = colBase + wc * 64 + in_ * 16 + lm;
            size_t rbase = (size_t)(rowBase + wr * 64 + im * 16 + quad * 4);
#pragma unroll
            for (int reg = 0; reg < 4; ++reg)
                l1[(rbase + reg) * H + col] = f2bf(acc[im][in_][reg]);
        }
    }
}

// ---- Layer 2: GELU + features + (768*9 -> 2), one wave per row ----
__global__ __launch_bounds__(256) void kan2_kernel(
    const unsigned short* __restrict__ l1, const float* __restrict__ bw,
    const float* __restrict__ sw, const float* __restrict__ sc,
    float* __restrict__ out)
{
    const int lane = threadIdx.x & 63;
    const int wv = threadIdx.x >> 6;
    const int n = blockIdx.x * 4 + wv;
    float a0 = 0.f, a1 = 0.f;
#pragma unroll
    for (int ii = 0; ii < H / 64; ++ii) {
        int i = lane + ii * 64;
        float h = bf2f(l1[(size_t)n * H + i]);
        float u = gelu_exact(h);
        float f0 = silu_f(u);
        float b[8];
        kan_bases(u, b);
        float bw0 = bw[i], bw1 = bw[H + i];
        float s0 = sc[i], s1 = sc[H + i];
        const float4* p0 = (const float4*)(sw + (size_t)i * 8);
        const float4* p1 = (const float4*)(sw + (size_t)(H + i) * 8);
        float4 w00 = p0[0], w01 = p0[1];
        float4 w10 = p1[0], w11 = p1[1];
        float t0 = b[0] * w00.x + b[1] * w00.y + b[2] * w00.z + b[3] * w00.w
                 + b[4] * w01.x + b[5] * w01.y + b[6] * w01.z + b[7] * w01.w;
        float t1 = b[0] * w10.x + b[1] * w10.y + b[2] * w10.z + b[3] * w10.w
                 + b[4] * w11.x + b[5] * w11.y + b[6] * w11.z + b[7] * w11.w;
        a0 += f0 * bw0 + s0 * t0;
        a1 += f0 * bw1 + s1 * t1;
    }
#pragma unroll
    for (int off = 32; off > 0; off >>= 1) {
        a0 += __shfl_down(a0, off, 64);
        a1 += __shfl_down(a1, off, 64);
    }
    if (lane == 0) {
        out[(size_t)n * 2 + 0] = a0;
        out[(size_t)n * 2 + 1] = a1;
    }
}

extern "C" void kernel_launch(void* const* d_in, const int* in_sizes, int n_in,
                              void* d_out, int out_size, void* d_ws, size_t ws_size,
                              hipStream_t stream) {
    const float* hidden = (const float*)d_in[0];
    const float* bw1    = (const float*)d_in[1];
    const float* sw1    = (const float*)d_in[2];
    const float* sc1    = (const float*)d_in[3];
    const float* bw2    = (const float*)d_in[4];
    const float* sw2    = (const float*)d_in[5];
    const float* sc2    = (const float*)d_in[6];
    float* out = (float*)d_out;

    const size_t l1_elems = (size_t)NROWS * H;     // 25.2 MB bf16
    const size_t wp_elems = (size_t)H * KEXP;      // 10.6 MB bf16

    unsigned short* l1 = (unsigned short*)d_ws;
    unsigned short* wp = l1 + l1_elems;
    unsigned short* F  = wp + wp_elems;            // 226.5 MB bf16 (ws-verified r3)

    prep_w1<<<H, 256, 0, stream>>>(bw1, sw1, sc1, wp);
    expand_f<<<NROWS, 256, 0, stream>>>(hidden, F);
    kan1_gemm<<<768, 256, 0, stream>>>(F, wp, l1);
    kan2_kernel<<<NROWS / 4, 256, 0, stream>>>(l1, bw2, sw2, sc2, out);
}